// Round 6
// baseline (465.709 us; speedup 1.0000x reference)
//
#include <hip/hip_runtime.h>
#include <hip/hip_bf16.h>

#define FEAT 256
#define HID 128
#define CLASSES 32
#define LAYERS 3

typedef float f4 __attribute__((ext_vector_type(4)));
typedef float f2 __attribute__((ext_vector_type(2)));
typedef __attribute__((ext_vector_type(8))) short short8;
typedef __attribute__((ext_vector_type(4))) float f32x4;
typedef unsigned int u32;
typedef __attribute__((ext_vector_type(4))) unsigned int u32x4;
typedef __attribute__((ext_vector_type(2))) unsigned int u32x2;

// split fp32 into bf16 hi + bf16 lo (RNE); v - hf is exact in fp32
__device__ __forceinline__ void split_bf16(float v, short& hi, short& lo) {
    unsigned u = __float_as_uint(v);
    unsigned r = (u + 0x7FFF + ((u >> 16) & 1)) >> 16;
    hi = (short)r;
    float hf = __uint_as_float(r << 16);
    float d = v - hf;
    unsigned u2 = __float_as_uint(d);
    unsigned r2 = (u2 + 0x7FFF + ((u2 >> 16) & 1)) >> 16;
    lo = (short)r2;
}

// pack fp32 into u32 = (bf16hi<<16) | bf16lo
__device__ __forceinline__ u32 pack_bf16(float v) {
    short h, l;
    split_bf16(v, h, l);
    return ((u32)(unsigned short)h << 16) | (u32)(unsigned short)l;
}

// ---------------- CSR build ----------------

__global__ void count_kernel(const int* __restrict__ dst, int* __restrict__ counts, int E) {
    int e = blockIdx.x * blockDim.x + threadIdx.x;
    if (e < E) atomicAdd(&counts[dst[e]], 1);
}

__global__ void partial_kernel(const int* __restrict__ counts, int* __restrict__ partials, int N) {
    int t = threadIdx.x;
    int i = blockIdx.x * 256 + t;
    int v = (i < N) ? counts[i] : 0;
#pragma unroll
    for (int off = 32; off >= 1; off >>= 1) v += __shfl_down(v, off, 64);
    __shared__ int ws[4];
    if ((t & 63) == 0) ws[t >> 6] = v;
    __syncthreads();
    if (t == 0) partials[blockIdx.x] = ws[0] + ws[1] + ws[2] + ws[3];
}

__global__ void scan_partials_kernel(const int* __restrict__ partials, int* __restrict__ poff, int NB) {
    int t = threadIdx.x, lane = t & 63, w = t >> 6;
    int v = (t < NB) ? partials[t] : 0;
    int x = v;
#pragma unroll
    for (int off = 1; off < 64; off <<= 1) {
        int y = __shfl_up(x, off, 64);
        if (lane >= off) x += y;
    }
    __shared__ int ws[4];
    if (lane == 63) ws[w] = x;
    __syncthreads();
    int woff = 0;
    for (int k = 0; k < w; ++k) woff += ws[k];
    if (t < NB) poff[t] = woff + x - v;
}

__global__ void scan_final_kernel(const int* __restrict__ counts, const int* __restrict__ poff,
                                  int* __restrict__ row_off, int* __restrict__ cursor, int N) {
    int t = threadIdx.x, lane = t & 63, w = t >> 6;
    int i = blockIdx.x * 256 + t;
    int v = (i < N) ? counts[i] : 0;
    int x = v;
#pragma unroll
    for (int off = 1; off < 64; off <<= 1) {
        int y = __shfl_up(x, off, 64);
        if (lane >= off) x += y;
    }
    __shared__ int ws[4];
    if (lane == 63) ws[w] = x;
    __syncthreads();
    int woff = 0;
    for (int k = 0; k < w; ++k) woff += ws[k];
    int excl = poff[blockIdx.x] + woff + x - v;
    if (i < N) {
        row_off[i] = excl;
        cursor[i] = excl;
        if (i == N - 1) row_off[N] = excl + v;
    }
}

__global__ void fill_kernel(const int* __restrict__ src, const int* __restrict__ dst,
                            int* __restrict__ cursor, int* __restrict__ csr_src, int E) {
    int e = blockIdx.x * blockDim.x + threadIdx.x;
    if (e < E) {
        int pos = atomicAdd(&cursor[dst[e]], 1);
        csr_src[pos] = src[e];
    }
}

// ---------------- weight prep: transposed bf16 hi/lo tables ----------------
__global__ void prep_emb_kernel(const float* __restrict__ emb_w,
                                unsigned short* __restrict__ hi, unsigned short* __restrict__ lo) {
    int idx = blockIdx.x * 256 + threadIdx.x;  // 128*256
    if (idx >= 128 * 256) return;
    int n = idx >> 8, k = idx & 255;
    short h, l;
    split_bf16(emb_w[k * 128 + n], h, l);
    hi[n * 256 + k] = (unsigned short)h;
    lo[n * 256 + k] = (unsigned short)l;
}

__global__ void prep_layer_kernel(const float* __restrict__ rel_w, const float* __restrict__ root_w,
                                  unsigned short* __restrict__ hi, unsigned short* __restrict__ lo) {
    int idx = blockIdx.x * 256 + threadIdx.x;  // 3*128*256
    if (idx >= 3 * 128 * 256) return;
    int l = idx >> 15;
    int r = idx & 32767;
    int n = r >> 8, k = r & 255;
    float w = (k < 128) ? rel_w[l * 16384 + k * 128 + n] : root_w[l * 16384 + (k - 128) * 128 + n];
    short h, lw;
    split_bf16(w, h, lw);
    hi[idx] = (unsigned short)h;
    lo[idx] = (unsigned short)lw;
}

__global__ void prep_head_kernel(const float* __restrict__ head_w,
                                 unsigned short* __restrict__ hi, unsigned short* __restrict__ lo) {
    int idx = blockIdx.x * 256 + threadIdx.x;  // 64*128
    if (idx >= 64 * 128) return;
    int c = idx >> 7, k = idx & 127;
    float w = (c < 32) ? head_w[k * 32 + c] : head_w[(128 + k) * 32 + (c - 32)];
    short h, l;
    split_bf16(w, h, l);
    hi[c * 128 + k] = (unsigned short)h;
    lo[c * 128 + k] = (unsigned short)l;
}

// ---------------- MFMA split-bf16 GEMM with LDS-staged B ----------------
// out[M x NCOL] = act( concatK(A0|A1)[M x KTOT] @ W[KTOT x NCOL] + bias )
// W pre-transposed bf16 hi/lo: Whi/Wlo[n][k] (n-major, stride KTOT).
// AFMT: 0 = A fp32 (split in-register), 1 = A packed u32 (bf16hi<<16|bf16lo).
// PACKOUT: epilogue writes packed u32 vs plain fp32.
// Block = 256 threads = 4 waves; wave w owns rows [blk*64 + w*16, +16).
// 64 rows/block (not 128): grid ~782 -> ~3 blocks/CU, so the per-chunk
// ds_write->barrier->ds_read->MFMA->barrier chain of one block overlaps other
// blocks' compute (round-5 counters: all pipes idle at 1.5 blocks/CU).
// Per K-chunk (32), B (all NCOL cols, hi+lo) staged once per block into LDS,
// reg-staged one chunk ahead; A register-prefetched one chunk ahead.
template <int NCOL, int KTOT, bool RELU, int AFMT, bool PACKOUT>
__global__ __launch_bounds__(256) void gemm_mfma(
    const void* __restrict__ A0v, int lda0,
    const void* __restrict__ A1v, int lda1, int K0,
    const unsigned short* __restrict__ Whi, const unsigned short* __restrict__ Wlo,
    const float* __restrict__ bias, void* __restrict__ outv, int M) {
    constexpr int NCHUNK = KTOT / 32;
    constexpr int NCT = NCOL / 16;     // 8 (NCOL=128) or 4 (NCOL=64)
    constexpr int CB = NCOL * 128;     // LDS bytes per chunk (hi+lo)
    constexpr int NI = NCT * 2;        // stage instrs per chunk (per block)
    constexpr int NIW = NI / 4;        // per wave: 4 or 2

    __shared__ unsigned char lds[CB];

    const u32* A0 = (const u32*)A0v;
    const u32* A1 = (const u32*)A1v;

    int wv = threadIdx.x >> 6;
    int lane = threadIdx.x & 63;
    int m16 = lane & 15;
    int quad = lane >> 4;
    int rowbase = blockIdx.x * 64 + wv * 16;

    int arow = rowbase + m16;
    arow = (arow < M) ? arow : (M - 1);  // clamp reads; stores guarded below

    auto g_src = [&](int i, int kc) -> const unsigned short* {
        const unsigned short* W = (i & 1) ? Wlo : Whi;
        int cb = (i >> 1) * 16;
        return W + (size_t)(cb + (lane >> 2)) * KTOT + kc * 32 + (lane & 3) * 8;
    };
    auto l_dst = [&](int i) -> unsigned char* {
        int t = i & 1;
        int cb = (i >> 1) * 16;
        return lds + t * (NCOL * 64) + cb * 64 + lane * 16;
    };
    auto aptr = [&](int kc) -> const u32* {
        bool second = (kc * 32 >= K0);
        const u32* Ab = second ? A1 : A0;
        int lda = second ? lda1 : lda0;
        int kofs = kc * 32 - (second ? K0 : 0);
        return Ab + (size_t)arow * lda + kofs + quad * 8;
    };

    f32x4 acc[NCT] = {};
    float bcol[NCT];
#pragma unroll
    for (int ct = 0; ct < NCT; ++ct) bcol[ct] = bias ? bias[ct * 16 + m16] : 0.f;

    // prologue: issue chunk-0 B-stage loads and A loads
    f4 stg[NIW];
#pragma unroll
    for (int ii = 0; ii < NIW; ++ii) stg[ii] = *(const f4*)(const void*)g_src(wv * NIW + ii, 0);
    u32x4 ra0, ra1;
    {
        const u32* p = aptr(0);
        ra0 = *(const u32x4*)p;
        ra1 = *(const u32x4*)(p + 4);
    }

#pragma unroll
    for (int kc = 0; kc < NCHUNK; ++kc) {
        // 1. commit staged B for this chunk to LDS (waits on stg's loads)
#pragma unroll
        for (int ii = 0; ii < NIW; ++ii) *(f4*)(void*)l_dst(wv * NIW + ii) = stg[ii];

        // 2. issue next chunk's global loads (B stage + A) -- fly during convert+MFMA
        u32x4 na0, na1;
        if (kc + 1 < NCHUNK) {
#pragma unroll
            for (int ii = 0; ii < NIW; ++ii) stg[ii] = *(const f4*)(const void*)g_src(wv * NIW + ii, kc + 1);
            const u32* p = aptr(kc + 1);
            na0 = *(const u32x4*)p;
            na1 = *(const u32x4*)(p + 4);
        }

        // 3. build A fragments for current chunk
        short8 Ah, Al;
        {
            u32 raw[8] = {ra0[0], ra0[1], ra0[2], ra0[3], ra1[0], ra1[1], ra1[2], ra1[3]};
            if (AFMT == 0) {
#pragma unroll
                for (int j = 0; j < 8; ++j) {
                    short h, l;
                    split_bf16(__uint_as_float(raw[j]), h, l);
                    Ah[j] = h;
                    Al[j] = l;
                }
            } else {
                union { short8 s; u32x4 u; } H, L;
#pragma unroll
                for (int p = 0; p < 4; ++p) {
                    H.u[p] = __builtin_amdgcn_perm(raw[2 * p + 1], raw[2 * p], 0x07060302u);
                    L.u[p] = __builtin_amdgcn_perm(raw[2 * p + 1], raw[2 * p], 0x05040100u);
                }
                Ah = H.s;
                Al = L.s;
            }
        }

        __syncthreads();  // B stage visible to all waves

        // 4. compute from LDS: per ct, 2 ds_read_b128 + 3 MFMAs
#pragma unroll
        for (int ct = 0; ct < NCT; ++ct) {
            const unsigned char* ph = lds + (ct * 16 + m16) * 64 + quad * 16;
            short8 Bh = *(const short8*)(const void*)ph;
            short8 Bl = *(const short8*)(const void*)(ph + NCOL * 64);
            acc[ct] = __builtin_amdgcn_mfma_f32_16x16x32_bf16(Ah, Bh, acc[ct], 0, 0, 0);
            acc[ct] = __builtin_amdgcn_mfma_f32_16x16x32_bf16(Al, Bh, acc[ct], 0, 0, 0);
            acc[ct] = __builtin_amdgcn_mfma_f32_16x16x32_bf16(Ah, Bl, acc[ct], 0, 0, 0);
        }

        if (kc + 1 < NCHUNK) {
            ra0 = na0;
            ra1 = na1;
        }

        __syncthreads();  // all waves done reading before next iter's ds_write
    }

    // epilogue: C/D layout col = lane&15, row = quad*4 + reg
#pragma unroll
    for (int r = 0; r < 4; ++r) {
        int row = rowbase + quad * 4 + r;
        if (row < M) {
#pragma unroll
            for (int ct = 0; ct < NCT; ++ct) {
                float v = acc[ct][r] + bcol[ct];
                if (RELU) v = fmaxf(v, 0.f);
                size_t idx = (size_t)row * NCOL + ct * 16 + m16;
                if (PACKOUT) ((u32*)outv)[idx] = pack_bf16(v);
                else ((float*)outv)[idx] = v;
            }
        }
    }
}

// ---------------- aggregation (CSR gather-sum, 4-wide pipelined MLP) ----------------
// x rows are packed u32 (bf16hi<<16|bf16lo); reconstruct v = hi + lo in fp32,
// accumulate fp32, epilogue re-packs. Extraction VALU hides under gather latency.
__global__ void aggregate_kernel(const u32* __restrict__ x, const int* __restrict__ row_off,
                                 const int* __restrict__ csr, u32* __restrict__ agg, int N) {
    int gw = (blockIdx.x * 256 + threadIdx.x) >> 6;
    int lane = threadIdx.x & 63;
    if (gw >= N) return;
    int beg = row_off[gw], end = row_off[gw + 1];
    int cofs = lane * 2;

    f2 a0 = (f2)0.f, a1 = (f2)0.f, a2 = (f2)0.f, a3 = (f2)0.f;

    auto unp = [](u32x2 u) -> f2 {
        f2 r;
        r[0] = __uint_as_float(u[0] & 0xFFFF0000u) + __uint_as_float(u[0] << 16);
        r[1] = __uint_as_float(u[1] & 0xFFFF0000u) + __uint_as_float(u[1] << 16);
        return r;
    };

    int nfull = (end - beg) >> 2;
    int j = beg;
    if (nfull > 0) {
        int s0 = csr[j], s1 = csr[j + 1], s2 = csr[j + 2], s3 = csr[j + 3];
        for (int b = 1; b < nfull; ++b) {
            u32x2 v0 = *(const u32x2*)&x[(size_t)s0 * HID + cofs];
            u32x2 v1 = *(const u32x2*)&x[(size_t)s1 * HID + cofs];
            u32x2 v2 = *(const u32x2*)&x[(size_t)s2 * HID + cofs];
            u32x2 v3 = *(const u32x2*)&x[(size_t)s3 * HID + cofs];
            int jn = j + 4;
            s0 = csr[jn]; s1 = csr[jn + 1]; s2 = csr[jn + 2]; s3 = csr[jn + 3];
            a0 += unp(v0); a1 += unp(v1); a2 += unp(v2); a3 += unp(v3);
            j = jn;
        }
        u32x2 v0 = *(const u32x2*)&x[(size_t)s0 * HID + cofs];
        u32x2 v1 = *(const u32x2*)&x[(size_t)s1 * HID + cofs];
        u32x2 v2 = *(const u32x2*)&x[(size_t)s2 * HID + cofs];
        u32x2 v3 = *(const u32x2*)&x[(size_t)s3 * HID + cofs];
        a0 += unp(v0); a1 += unp(v1); a2 += unp(v2); a3 += unp(v3);
        j += 4;
    }

    int rem = end - j;
    if (rem > 0) {
        int e1 = end - 1;
        int t0 = csr[j];
        int t1 = csr[min(j + 1, e1)];
        int t2 = csr[min(j + 2, e1)];
        u32x2 w0 = *(const u32x2*)&x[(size_t)t0 * HID + cofs];
        u32x2 w1 = *(const u32x2*)&x[(size_t)t1 * HID + cofs];
        u32x2 w2 = *(const u32x2*)&x[(size_t)t2 * HID + cofs];
        a0 += unp(w0);
        if (rem > 1) a1 += unp(w1);
        if (rem > 2) a2 += unp(w2);
    }

    f2 a = (a0 + a2) + (a1 + a3);
    u32x2 o;
    o[0] = pack_bf16(a[0]);
    o[1] = pack_bf16(a[1]);
    *(u32x2*)&agg[(size_t)gw * HID + cofs] = o;
}

// ---------------- edge head ----------------
__global__ void edge_out_kernel(const int* __restrict__ src, const int* __restrict__ dst,
                                const float* __restrict__ pspd, const float* __restrict__ head_b,
                                float* __restrict__ out, int E) {
    int idx = blockIdx.x * blockDim.x + threadIdx.x;
    int e = idx >> 3;
    int c4 = (idx & 7) * 4;
    if (e >= E) return;
    int s = src[e], d = dst[e];
    f4 a = *(const f4*)&pspd[(size_t)s * 64 + c4];
    f4 b = *(const f4*)&pspd[(size_t)d * 64 + 32 + c4];
    f4 hb = *(const f4*)&head_b[c4];
    f4 o = a + b + hb;
    *(f4*)&out[(size_t)e * CLASSES + c4] = o;
}

// ---------------- launcher ----------------

extern "C" void kernel_launch(void* const* d_in, const int* in_sizes, int n_in,
                              void* d_out, int out_size, void* d_ws, size_t ws_size,
                              hipStream_t stream) {
    const float* feat   = (const float*)d_in[0];
    const int*   eidx   = (const int*)d_in[1];
    const float* emb_w  = (const float*)d_in[2];
    const float* emb_b  = (const float*)d_in[3];
    const float* rel_w  = (const float*)d_in[4];
    const float* rel_b  = (const float*)d_in[5];
    const float* root_w = (const float*)d_in[6];
    const float* head_w = (const float*)d_in[7];
    const float* head_b = (const float*)d_in[8];
    float* out = (float*)d_out;

    int N = in_sizes[0] / FEAT;
    int E = in_sizes[1] / 2;
    const int* src = eidx;
    const int* dst = eidx + E;

    // workspace layout: activation u32 buffers, then ints, then ushort weight tables
    u32* xA  = (u32*)d_ws;                  // N*128 packed
    u32* xB  = xA + (size_t)N * HID;        // N*128 packed
    u32* agg = xB + (size_t)N * HID;        // N*128 packed (pspd reuses as N*64 fp32)
    int* counts   = (int*)(agg + (size_t)N * HID);  // N
    int* row_off  = counts + N;                     // N+1
    int* cursor   = row_off + (N + 1);              // N
    int* csr_src  = cursor + N;                     // E
    int* partials = csr_src + E;                    // 256
    int* poff     = partials + 256;                 // 256
    int* iend     = poff + 256;
    // pad int region to 16B boundary
    size_t ioff = (size_t)(iend - (int*)d_ws);
    ioff = (ioff + 3) & ~(size_t)3;
    unsigned short* we_hi = (unsigned short*)((int*)d_ws + ioff);
    unsigned short* we_lo = we_hi + 128 * 256;
    unsigned short* wl_hi = we_lo + 128 * 256;      // 3*128*256
    unsigned short* wl_lo = wl_hi + 3 * 128 * 256;  // 3*128*256
    unsigned short* wp_hi = wl_lo + 3 * 128 * 256;  // 64*128
    unsigned short* wp_lo = wp_hi + 64 * 128;       // 64*128

    int NB = (N + 255) / 256;

    hipMemsetAsync(counts, 0, (size_t)N * sizeof(int), stream);
    count_kernel<<<(E + 255) / 256, 256, 0, stream>>>(dst, counts, E);
    partial_kernel<<<NB, 256, 0, stream>>>(counts, partials, N);
    scan_partials_kernel<<<1, 256, 0, stream>>>(partials, poff, NB);
    scan_final_kernel<<<NB, 256, 0, stream>>>(counts, poff, row_off, cursor, N);
    fill_kernel<<<(E + 255) / 256, 256, 0, stream>>>(src, dst, cursor, csr_src, E);

    prep_emb_kernel<<<(128 * 256 + 255) / 256, 256, 0, stream>>>(emb_w, we_hi, we_lo);
    prep_layer_kernel<<<(3 * 128 * 256 + 255) / 256, 256, 0, stream>>>(rel_w, root_w, wl_hi, wl_lo);
    prep_head_kernel<<<(64 * 128 + 255) / 256, 256, 0, stream>>>(head_w, wp_hi, wp_lo);

    int grid = (N + 63) / 64;
    // embed: xA = pack(relu(feat @ emb_w + emb_b)); A is fp32
    gemm_mfma<HID, FEAT, true, 0, true><<<grid, 256, 0, stream>>>(
        feat, FEAT, nullptr, 0, FEAT, we_hi, we_lo, emb_b, xA, N);

    const u32* xin = xA;
    u32* xout = xB;
    for (int l = 0; l < LAYERS; ++l) {
        aggregate_kernel<<<(N * 64 + 255) / 256, 256, 0, stream>>>(xin, row_off, csr_src, agg, N);
        gemm_mfma<HID, 2 * HID, true, 1, true><<<grid, 256, 0, stream>>>(
            agg, HID, xin, HID, HID,
            wl_hi + (size_t)l * 128 * 256, wl_lo + (size_t)l * 128 * 256,
            rel_b + (size_t)l * HID, xout, N);
        u32* tmp = (u32*)xin; xin = xout; xout = tmp;
    }

    // pspd = x @ Wpp (no bias/relu), fp32 out; reuse agg
    float* pspd = (float*)agg;
    gemm_mfma<64, HID, false, 1, false><<<grid, 256, 0, stream>>>(
        xin, HID, nullptr, 0, HID, wp_hi, wp_lo, nullptr, pspd, N);

    edge_out_kernel<<<((size_t)E * 8 + 255) / 256, 256, 0, stream>>>(src, dst, pspd, head_b, out, E);
}

// Round 7
// 436.078 us; speedup vs baseline: 1.0679x; 1.0679x over previous
//
#include <hip/hip_runtime.h>
#include <hip/hip_bf16.h>

#define FEAT 256
#define HID 128
#define CLASSES 32
#define LAYERS 3

typedef float f4 __attribute__((ext_vector_type(4)));
typedef float f2 __attribute__((ext_vector_type(2)));
typedef __attribute__((ext_vector_type(8))) short short8;
typedef __attribute__((ext_vector_type(4))) float f32x4;

// split fp32 into bf16 hi + bf16 lo (RNE); v - hf is exact in fp32
__device__ __forceinline__ void split_bf16(float v, short& hi, short& lo) {
    unsigned u = __float_as_uint(v);
    unsigned r = (u + 0x7FFF + ((u >> 16) & 1)) >> 16;
    hi = (short)r;
    float hf = __uint_as_float(r << 16);
    float d = v - hf;
    unsigned u2 = __float_as_uint(d);
    unsigned r2 = (u2 + 0x7FFF + ((u2 >> 16) & 1)) >> 16;
    lo = (short)r2;
}

// ---------------- CSR build ----------------

__global__ void count_kernel(const int* __restrict__ dst, int* __restrict__ counts, int E) {
    int e = blockIdx.x * blockDim.x + threadIdx.x;
    if (e < E) atomicAdd(&counts[dst[e]], 1);
}

__global__ void partial_kernel(const int* __restrict__ counts, int* __restrict__ partials, int N) {
    int t = threadIdx.x;
    int i = blockIdx.x * 256 + t;
    int v = (i < N) ? counts[i] : 0;
#pragma unroll
    for (int off = 32; off >= 1; off >>= 1) v += __shfl_down(v, off, 64);
    __shared__ int ws[4];
    if ((t & 63) == 0) ws[t >> 6] = v;
    __syncthreads();
    if (t == 0) partials[blockIdx.x] = ws[0] + ws[1] + ws[2] + ws[3];
}

__global__ void scan_partials_kernel(const int* __restrict__ partials, int* __restrict__ poff, int NB) {
    int t = threadIdx.x, lane = t & 63, w = t >> 6;
    int v = (t < NB) ? partials[t] : 0;
    int x = v;
#pragma unroll
    for (int off = 1; off < 64; off <<= 1) {
        int y = __shfl_up(x, off, 64);
        if (lane >= off) x += y;
    }
    __shared__ int ws[4];
    if (lane == 63) ws[w] = x;
    __syncthreads();
    int woff = 0;
    for (int k = 0; k < w; ++k) woff += ws[k];
    if (t < NB) poff[t] = woff + x - v;
}

__global__ void scan_final_kernel(const int* __restrict__ counts, const int* __restrict__ poff,
                                  int* __restrict__ row_off, int* __restrict__ cursor, int N) {
    int t = threadIdx.x, lane = t & 63, w = t >> 6;
    int i = blockIdx.x * 256 + t;
    int v = (i < N) ? counts[i] : 0;
    int x = v;
#pragma unroll
    for (int off = 1; off < 64; off <<= 1) {
        int y = __shfl_up(x, off, 64);
        if (lane >= off) x += y;
    }
    __shared__ int ws[4];
    if (lane == 63) ws[w] = x;
    __syncthreads();
    int woff = 0;
    for (int k = 0; k < w; ++k) woff += ws[k];
    int excl = poff[blockIdx.x] + woff + x - v;
    if (i < N) {
        row_off[i] = excl;
        cursor[i] = excl;
        if (i == N - 1) row_off[N] = excl + v;
    }
}

__global__ void fill_kernel(const int* __restrict__ src, const int* __restrict__ dst,
                            int* __restrict__ cursor, int* __restrict__ csr_src, int E) {
    int e = blockIdx.x * blockDim.x + threadIdx.x;
    if (e < E) {
        int pos = atomicAdd(&cursor[dst[e]], 1);
        csr_src[pos] = src[e];
    }
}

// ---------------- weight prep: transposed bf16 hi/lo tables ----------------
__global__ void prep_emb_kernel(const float* __restrict__ emb_w,
                                unsigned short* __restrict__ hi, unsigned short* __restrict__ lo) {
    int idx = blockIdx.x * 256 + threadIdx.x;  // 128*256
    if (idx >= 128 * 256) return;
    int n = idx >> 8, k = idx & 255;
    short h, l;
    split_bf16(emb_w[k * 128 + n], h, l);
    hi[n * 256 + k] = (unsigned short)h;
    lo[n * 256 + k] = (unsigned short)l;
}

__global__ void prep_layer_kernel(const float* __restrict__ rel_w, const float* __restrict__ root_w,
                                  unsigned short* __restrict__ hi, unsigned short* __restrict__ lo) {
    int idx = blockIdx.x * 256 + threadIdx.x;  // 3*128*256
    if (idx >= 3 * 128 * 256) return;
    int l = idx >> 15;
    int r = idx & 32767;
    int n = r >> 8, k = r & 255;
    float w = (k < 128) ? rel_w[l * 16384 + k * 128 + n] : root_w[l * 16384 + (k - 128) * 128 + n];
    short h, lw;
    split_bf16(w, h, lw);
    hi[idx] = (unsigned short)h;
    lo[idx] = (unsigned short)lw;
}

__global__ void prep_head_kernel(const float* __restrict__ head_w,
                                 unsigned short* __restrict__ hi, unsigned short* __restrict__ lo) {
    int idx = blockIdx.x * 256 + threadIdx.x;  // 64*128
    if (idx >= 64 * 128) return;
    int c = idx >> 7, k = idx & 127;
    float w = (c < 32) ? head_w[k * 32 + c] : head_w[(128 + k) * 32 + (c - 32)];
    short h, l;
    split_bf16(w, h, l);
    hi[c * 128 + k] = (unsigned short)h;
    lo[c * 128 + k] = (unsigned short)l;
}

// ---------------- MFMA split-bf16 GEMM, double-buffered LDS B, 1 barrier/chunk ----------------
// out[M x NCOL] = act( concatK(A0|A1)[M x KTOT] @ W[KTOT x NCOL] + bias )
// W pre-transposed bf16 hi/lo: Whi/Wlo[n][k] (n-major, stride KTOT).
// Block = 256 threads = 4 waves; wave w owns rows [blk*128 + w*32, +32) x all NCOL.
// Pipeline per chunk kc: ds_write chunk kc+1 into buf[p^1] (loads issued 2 chunks
// ahead -> vmcnt wait ~0), issue B loads kc+2 + A loads kc+1, convert A(kc),
// ds_read buf[p] + MFMA, ONE barrier. The barrier at end of kc-1 guarantees all
// waves finished reading buf[p^1] (they read it in kc-1), so the write is safe;
// the barrier at end of kc makes the write visible before kc+1 reads it.
template <int NCOL, int KTOT, bool RELU>
__global__ __launch_bounds__(256) void gemm_mfma(
    const float* __restrict__ A0, int lda0,
    const float* __restrict__ A1, int lda1, int K0,
    const unsigned short* __restrict__ Whi, const unsigned short* __restrict__ Wlo,
    const float* __restrict__ bias, float* __restrict__ out, int M) {
    constexpr int NCHUNK = KTOT / 32;
    constexpr int NCT = NCOL / 16;     // 8 (NCOL=128) or 4 (NCOL=64)
    constexpr int CB = NCOL * 128;     // LDS bytes per chunk buffer (hi+lo)
    constexpr int NI = NCT * 2;        // stage instrs per chunk (per block)
    constexpr int NIW = NI / 4;        // per wave: 4 or 2

    __shared__ unsigned char lds[2][CB];

    int wv = threadIdx.x >> 6;
    int lane = threadIdx.x & 63;
    int m16 = lane & 15;
    int quad = lane >> 4;
    int rowbase = blockIdx.x * 128 + wv * 32;

    int arow[2];
#pragma unroll
    for (int rt = 0; rt < 2; ++rt) {
        int r = rowbase + rt * 16 + m16;
        arow[rt] = (r < M) ? r : (M - 1);  // clamp reads; stores guarded below
    }

    // stage instr i: table t=i&1, cols [(i>>1)*16,+16); lane covers col cb+(lane>>2), quarter lane&3
    auto g_src = [&](int i, int kc) -> const unsigned short* {
        const unsigned short* W = (i & 1) ? Wlo : Whi;
        int cb = (i >> 1) * 16;
        return W + (size_t)(cb + (lane >> 2)) * KTOT + kc * 32 + (lane & 3) * 8;
    };
    auto dstoff = [&](int i) -> int {
        int t = i & 1;
        int cb = (i >> 1) * 16;
        return t * (NCOL * 64) + cb * 64 + lane * 16;
    };
    auto aptr = [&](int kc, int rt) -> const float* {
        bool second = (kc * 32 >= K0);
        const float* Ab = second ? A1 : A0;
        int lda = second ? lda1 : lda0;
        int kofs = kc * 32 - (second ? K0 : 0);
        return Ab + (size_t)arow[rt] * lda + kofs + quad * 8;
    };

    f32x4 acc[2][NCT] = {};
    float bcol[NCT];
#pragma unroll
    for (int ct = 0; ct < NCT; ++ct) bcol[ct] = bias ? bias[ct * 16 + m16] : 0.f;

    // ---- prologue ----
    f4 stg[NIW];
#pragma unroll
    for (int ii = 0; ii < NIW; ++ii) stg[ii] = *(const f4*)(const void*)g_src(wv * NIW + ii, 0);
    f4 ra[2][2];
#pragma unroll
    for (int rt = 0; rt < 2; ++rt) {
        const float* p = aptr(0, rt);
        ra[rt][0] = *(const f4*)p;
        ra[rt][1] = *(const f4*)(p + 4);
    }
    // commit chunk0 into buf0 (waits on chunk0 loads)
#pragma unroll
    for (int ii = 0; ii < NIW; ++ii) *(f4*)(void*)(&lds[0][dstoff(wv * NIW + ii)]) = stg[ii];
    // issue chunk1 B loads (will be written at kc=0)
    if (NCHUNK > 1) {
#pragma unroll
        for (int ii = 0; ii < NIW; ++ii) stg[ii] = *(const f4*)(const void*)g_src(wv * NIW + ii, 1);
    }
    __syncthreads();  // buf0 visible

#pragma unroll
    for (int kc = 0; kc < NCHUNK; ++kc) {
        int p = kc & 1;

        // 1. write chunk kc+1 into buf[p^1]; issue chunk kc+2 B loads
        if (kc + 1 < NCHUNK) {
#pragma unroll
            for (int ii = 0; ii < NIW; ++ii) *(f4*)(void*)(&lds[p ^ 1][dstoff(wv * NIW + ii)]) = stg[ii];
            if (kc + 2 < NCHUNK) {
#pragma unroll
                for (int ii = 0; ii < NIW; ++ii) stg[ii] = *(const f4*)(const void*)g_src(wv * NIW + ii, kc + 2);
            }
        }

        // 2. issue next chunk's A loads -- fly during convert+MFMA
        f4 na[2][2];
        if (kc + 1 < NCHUNK) {
#pragma unroll
            for (int rt = 0; rt < 2; ++rt) {
                const float* pn = aptr(kc + 1, rt);
                na[rt][0] = *(const f4*)pn;
                na[rt][1] = *(const f4*)(pn + 4);
            }
        }

        // 3. convert current A in-register
        short8 Ah[2], Al[2];
#pragma unroll
        for (int rt = 0; rt < 2; ++rt) {
            float av[8] = {ra[rt][0][0], ra[rt][0][1], ra[rt][0][2], ra[rt][0][3],
                           ra[rt][1][0], ra[rt][1][1], ra[rt][1][2], ra[rt][1][3]};
#pragma unroll
            for (int j = 0; j < 8; ++j) {
                short h, l;
                split_bf16(av[j], h, l);
                Ah[rt][j] = h;
                Al[rt][j] = l;
            }
        }

        // 4. compute from buf[p]: per ct, 2 ds_read_b128 + 6 MFMAs
#pragma unroll
        for (int ct = 0; ct < NCT; ++ct) {
            const unsigned char* ph = &lds[p][(ct * 16 + m16) * 64 + quad * 16];
            short8 Bh = *(const short8*)(const void*)ph;
            short8 Bl = *(const short8*)(const void*)(ph + NCOL * 64);
#pragma unroll
            for (int rt = 0; rt < 2; ++rt) {
                acc[rt][ct] = __builtin_amdgcn_mfma_f32_16x16x32_bf16(Ah[rt], Bh, acc[rt][ct], 0, 0, 0);
                acc[rt][ct] = __builtin_amdgcn_mfma_f32_16x16x32_bf16(Al[rt], Bh, acc[rt][ct], 0, 0, 0);
                acc[rt][ct] = __builtin_amdgcn_mfma_f32_16x16x32_bf16(Ah[rt], Bl, acc[rt][ct], 0, 0, 0);
            }
        }

        if (kc + 1 < NCHUNK) {
#pragma unroll
            for (int rt = 0; rt < 2; ++rt) {
                ra[rt][0] = na[rt][0];
                ra[rt][1] = na[rt][1];
            }
        }

        __syncthreads();  // reads of buf[p] done; writes to buf[p^1] visible
    }

    // epilogue: C/D layout col = lane&15, row = quad*4 + reg
#pragma unroll
    for (int rt = 0; rt < 2; ++rt) {
#pragma unroll
        for (int r = 0; r < 4; ++r) {
            int row = rowbase + rt * 16 + quad * 4 + r;
            if (row < M) {
#pragma unroll
                for (int ct = 0; ct < NCT; ++ct) {
                    float v = acc[rt][ct][r] + bcol[ct];
                    out[(size_t)row * NCOL + ct * 16 + m16] = RELU ? fmaxf(v, 0.f) : v;
                }
            }
        }
    }
}

// ---------------- aggregation (CSR gather-sum, 4-wide pipelined MLP) ----------------
__global__ void aggregate_kernel(const float* __restrict__ x, const int* __restrict__ row_off,
                                 const int* __restrict__ csr, float* __restrict__ agg, int N) {
    int gw = (blockIdx.x * 256 + threadIdx.x) >> 6;
    int lane = threadIdx.x & 63;
    if (gw >= N) return;
    int beg = row_off[gw], end = row_off[gw + 1];
    int cofs = lane * 2;

    f2 a0 = (f2)0.f, a1 = (f2)0.f, a2 = (f2)0.f, a3 = (f2)0.f;

    int nfull = (end - beg) >> 2;
    int j = beg;
    if (nfull > 0) {
        int s0 = csr[j], s1 = csr[j + 1], s2 = csr[j + 2], s3 = csr[j + 3];
        for (int b = 1; b < nfull; ++b) {
            f2 v0 = *(const f2*)&x[(size_t)s0 * HID + cofs];
            f2 v1 = *(const f2*)&x[(size_t)s1 * HID + cofs];
            f2 v2 = *(const f2*)&x[(size_t)s2 * HID + cofs];
            f2 v3 = *(const f2*)&x[(size_t)s3 * HID + cofs];
            int jn = j + 4;
            s0 = csr[jn]; s1 = csr[jn + 1]; s2 = csr[jn + 2]; s3 = csr[jn + 3];
            a0 += v0; a1 += v1; a2 += v2; a3 += v3;
            j = jn;
        }
        f2 v0 = *(const f2*)&x[(size_t)s0 * HID + cofs];
        f2 v1 = *(const f2*)&x[(size_t)s1 * HID + cofs];
        f2 v2 = *(const f2*)&x[(size_t)s2 * HID + cofs];
        f2 v3 = *(const f2*)&x[(size_t)s3 * HID + cofs];
        a0 += v0; a1 += v1; a2 += v2; a3 += v3;
        j += 4;
    }

    int rem = end - j;
    if (rem > 0) {
        int e1 = end - 1;
        int t0 = csr[j];
        int t1 = csr[min(j + 1, e1)];
        int t2 = csr[min(j + 2, e1)];
        f2 w0 = *(const f2*)&x[(size_t)t0 * HID + cofs];
        f2 w1 = *(const f2*)&x[(size_t)t1 * HID + cofs];
        f2 w2 = *(const f2*)&x[(size_t)t2 * HID + cofs];
        a0 += w0;
        if (rem > 1) a1 += w1;
        if (rem > 2) a2 += w2;
    }

    f2 a = (a0 + a2) + (a1 + a3);
    *(f2*)&agg[(size_t)gw * HID + cofs] = a;
}

// ---------------- edge head ----------------
__global__ void edge_out_kernel(const int* __restrict__ src, const int* __restrict__ dst,
                                const float* __restrict__ pspd, const float* __restrict__ head_b,
                                float* __restrict__ out, int E) {
    int idx = blockIdx.x * blockDim.x + threadIdx.x;
    int e = idx >> 3;
    int c4 = (idx & 7) * 4;
    if (e >= E) return;
    int s = src[e], d = dst[e];
    f4 a = *(const f4*)&pspd[(size_t)s * 64 + c4];
    f4 b = *(const f4*)&pspd[(size_t)d * 64 + 32 + c4];
    f4 hb = *(const f4*)&head_b[c4];
    f4 o = a + b + hb;
    *(f4*)&out[(size_t)e * CLASSES + c4] = o;
}

// ---------------- launcher ----------------

extern "C" void kernel_launch(void* const* d_in, const int* in_sizes, int n_in,
                              void* d_out, int out_size, void* d_ws, size_t ws_size,
                              hipStream_t stream) {
    const float* feat   = (const float*)d_in[0];
    const int*   eidx   = (const int*)d_in[1];
    const float* emb_w  = (const float*)d_in[2];
    const float* emb_b  = (const float*)d_in[3];
    const float* rel_w  = (const float*)d_in[4];
    const float* rel_b  = (const float*)d_in[5];
    const float* root_w = (const float*)d_in[6];
    const float* head_w = (const float*)d_in[7];
    const float* head_b = (const float*)d_in[8];
    float* out = (float*)d_out;

    int N = in_sizes[0] / FEAT;
    int E = in_sizes[1] / 2;
    const int* src = eidx;
    const int* dst = eidx + E;

    // workspace layout: floats, then ints, then ushort weight tables (16B-aligned)
    float* xA  = (float*)d_ws;               // N*128
    float* xB  = xA + (size_t)N * HID;       // N*128
    float* agg = xB + (size_t)N * HID;       // N*128 (pspd reuses as N*64)
    int* counts   = (int*)(agg + (size_t)N * HID);  // N
    int* row_off  = counts + N;                     // N+1
    int* cursor   = row_off + (N + 1);              // N
    int* csr_src  = cursor + N;                     // E
    int* partials = csr_src + E;                    // 256
    int* poff     = partials + 256;                 // 256
    int* iend     = poff + 256;
    // pad int region to 16B boundary
    size_t ioff = (size_t)(iend - (int*)d_ws);
    ioff = (ioff + 3) & ~(size_t)3;
    unsigned short* we_hi = (unsigned short*)((int*)d_ws + ioff);
    unsigned short* we_lo = we_hi + 128 * 256;
    unsigned short* wl_hi = we_lo + 128 * 256;      // 3*128*256
    unsigned short* wl_lo = wl_hi + 3 * 128 * 256;  // 3*128*256
    unsigned short* wp_hi = wl_lo + 3 * 128 * 256;  // 64*128
    unsigned short* wp_lo = wp_hi + 64 * 128;       // 64*128

    int NB = (N + 255) / 256;

    hipMemsetAsync(counts, 0, (size_t)N * sizeof(int), stream);
    count_kernel<<<(E + 255) / 256, 256, 0, stream>>>(dst, counts, E);
    partial_kernel<<<NB, 256, 0, stream>>>(counts, partials, N);
    scan_partials_kernel<<<1, 256, 0, stream>>>(partials, poff, NB);
    scan_final_kernel<<<NB, 256, 0, stream>>>(counts, poff, row_off, cursor, N);
    fill_kernel<<<(E + 255) / 256, 256, 0, stream>>>(src, dst, cursor, csr_src, E);

    prep_emb_kernel<<<(128 * 256 + 255) / 256, 256, 0, stream>>>(emb_w, we_hi, we_lo);
    prep_layer_kernel<<<(3 * 128 * 256 + 255) / 256, 256, 0, stream>>>(rel_w, root_w, wl_hi, wl_lo);
    prep_head_kernel<<<(64 * 128 + 255) / 256, 256, 0, stream>>>(head_w, wp_hi, wp_lo);

    int grid = (N + 127) / 128;
    // embed: x = relu(feat @ emb_w + emb_b)
    gemm_mfma<HID, FEAT, true><<<grid, 256, 0, stream>>>(
        feat, FEAT, nullptr, 0, FEAT, we_hi, we_lo, emb_b, xA, N);

    const float* xin = xA;
    float* xout = xB;
    for (int l = 0; l < LAYERS; ++l) {
        aggregate_kernel<<<(N * 64 + 255) / 256, 256, 0, stream>>>(xin, row_off, csr_src, agg, N);
        gemm_mfma<HID, 2 * HID, true><<<grid, 256, 0, stream>>>(
            agg, HID, xin, HID, HID,
            wl_hi + (size_t)l * 128 * 256, wl_lo + (size_t)l * 128 * 256,
            rel_b + (size_t)l * HID, xout, N);
        float* tmp = (float*)xin; xin = xout; xout = tmp;
    }

    // pspd = x @ Wpp (no bias/relu); reuse agg
    float* pspd = agg;
    gemm_mfma<64, HID, false><<<grid, 256, 0, stream>>>(
        xin, HID, nullptr, 0, HID, wp_hi, wp_lo, nullptr, pspd, N);

    edge_out_kernel<<<((size_t)E * 8 + 255) / 256, 256, 0, stream>>>(src, dst, pspd, head_b, out, E);
}

// Round 8
// 344.175 us; speedup vs baseline: 1.3531x; 1.2670x over previous
//
#include <hip/hip_runtime.h>
#include <hip/hip_bf16.h>

#define FEAT 256
#define HID 128
#define CLASSES 32
#define LAYERS 3

typedef float f4 __attribute__((ext_vector_type(4)));
typedef float f2 __attribute__((ext_vector_type(2)));
typedef __attribute__((ext_vector_type(8))) short short8;
typedef __attribute__((ext_vector_type(4))) float f32x4;
typedef unsigned int u32;
typedef __attribute__((ext_vector_type(4))) unsigned int u32x4;
typedef __attribute__((ext_vector_type(2))) unsigned int u32x2;

// fp32 -> bf16 RNE
__device__ __forceinline__ unsigned short bf16_rne(float v) {
    unsigned u = __float_as_uint(v);
    return (unsigned short)((u + 0x7FFF + ((u >> 16) & 1)) >> 16);
}
// pack two fp32 -> u32 of 2 bf16 (elem0 low, elem1 high)
__device__ __forceinline__ u32 bf16x2_rne(float a, float b) {
    return (u32)bf16_rne(a) | ((u32)bf16_rne(b) << 16);
}

// ---------------- CSR build ----------------

__global__ void count_kernel(const int* __restrict__ dst, int* __restrict__ counts, int E) {
    int e = blockIdx.x * blockDim.x + threadIdx.x;
    if (e < E) atomicAdd(&counts[dst[e]], 1);
}

__global__ void partial_kernel(const int* __restrict__ counts, int* __restrict__ partials, int N) {
    int t = threadIdx.x;
    int i = blockIdx.x * 256 + t;
    int v = (i < N) ? counts[i] : 0;
#pragma unroll
    for (int off = 32; off >= 1; off >>= 1) v += __shfl_down(v, off, 64);
    __shared__ int ws[4];
    if ((t & 63) == 0) ws[t >> 6] = v;
    __syncthreads();
    if (t == 0) partials[blockIdx.x] = ws[0] + ws[1] + ws[2] + ws[3];
}

__global__ void scan_partials_kernel(const int* __restrict__ partials, int* __restrict__ poff, int NB) {
    int t = threadIdx.x, lane = t & 63, w = t >> 6;
    int v = (t < NB) ? partials[t] : 0;
    int x = v;
#pragma unroll
    for (int off = 1; off < 64; off <<= 1) {
        int y = __shfl_up(x, off, 64);
        if (lane >= off) x += y;
    }
    __shared__ int ws[4];
    if (lane == 63) ws[w] = x;
    __syncthreads();
    int woff = 0;
    for (int k = 0; k < w; ++k) woff += ws[k];
    if (t < NB) poff[t] = woff + x - v;
}

__global__ void scan_final_kernel(const int* __restrict__ counts, const int* __restrict__ poff,
                                  int* __restrict__ row_off, int* __restrict__ cursor, int N) {
    int t = threadIdx.x, lane = t & 63, w = t >> 6;
    int i = blockIdx.x * 256 + t;
    int v = (i < N) ? counts[i] : 0;
    int x = v;
#pragma unroll
    for (int off = 1; off < 64; off <<= 1) {
        int y = __shfl_up(x, off, 64);
        if (lane >= off) x += y;
    }
    __shared__ int ws[4];
    if (lane == 63) ws[w] = x;
    __syncthreads();
    int woff = 0;
    for (int k = 0; k < w; ++k) woff += ws[k];
    int excl = poff[blockIdx.x] + woff + x - v;
    if (i < N) {
        row_off[i] = excl;
        cursor[i] = excl;
        if (i == N - 1) row_off[N] = excl + v;
    }
}

__global__ void fill_kernel(const int* __restrict__ src, const int* __restrict__ dst,
                            int* __restrict__ cursor, int* __restrict__ csr_src, int E) {
    int e = blockIdx.x * blockDim.x + threadIdx.x;
    if (e < E) {
        int pos = atomicAdd(&cursor[dst[e]], 1);
        csr_src[pos] = src[e];
    }
}

// ---------------- weight prep: transposed single-bf16 tables ----------------
// we:  [n=128][k=256]  from emb_w[k][n]
// wl:  3 x [n=128][k=256]; k<128 -> rel_w[l][k][n], k>=128 -> root_w[l][k-128][n]
// wp:  [c=64][k=128]; c<32 -> head_w[k][c], else head_w[128+k][c-32]
__global__ void prep_emb_kernel(const float* __restrict__ emb_w, unsigned short* __restrict__ w) {
    int idx = blockIdx.x * 256 + threadIdx.x;  // 128*256
    if (idx >= 128 * 256) return;
    int n = idx >> 8, k = idx & 255;
    w[n * 256 + k] = bf16_rne(emb_w[k * 128 + n]);
}

__global__ void prep_layer_kernel(const float* __restrict__ rel_w, const float* __restrict__ root_w,
                                  unsigned short* __restrict__ w) {
    int idx = blockIdx.x * 256 + threadIdx.x;  // 3*128*256
    if (idx >= 3 * 128 * 256) return;
    int l = idx >> 15;
    int r = idx & 32767;
    int n = r >> 8, k = r & 255;
    float v = (k < 128) ? rel_w[l * 16384 + k * 128 + n] : root_w[l * 16384 + (k - 128) * 128 + n];
    w[idx] = bf16_rne(v);
}

__global__ void prep_head_kernel(const float* __restrict__ head_w, unsigned short* __restrict__ w) {
    int idx = blockIdx.x * 256 + threadIdx.x;  // 64*128
    if (idx >= 64 * 128) return;
    int c = idx >> 7, k = idx & 127;
    float v = (c < 32) ? head_w[k * 32 + c] : head_w[(128 + k) * 32 + (c - 32)];
    w[c * 128 + k] = bf16_rne(v);
}

// ---------------- MFMA bf16 GEMM, double-buffered LDS B, 1 barrier/chunk ----------------
// out[M x NCOL] = act( concatK(A0|A1)[M x KTOT] @ W[KTOT x NCOL] + bias )
// W pre-transposed single bf16: W[n][k] (n-major, stride KTOT).
// AFMT: 0 = A fp32 (cvt to bf16 in-register), 1 = A bf16 (direct fragment load).
// PACKOUT: epilogue writes bf16 (ushort) vs fp32.
// Block = 256 threads = 4 waves; wave w owns rows [blk*128 + w*32, +32) x all NCOL.
// Pipeline per chunk kc (K=32): ds_write chunk kc+1 into buf[p^1] (loads issued 2
// chunks ahead), issue B loads kc+2 + A loads kc+1, build A frags, ds_read buf[p]
// + 1 MFMA per (ct,rt), ONE barrier.
template <int NCOL, int KTOT, bool RELU, int AFMT, bool PACKOUT>
__global__ __launch_bounds__(256) void gemm_mfma(
    const void* __restrict__ A0v, int lda0,
    const void* __restrict__ A1v, int lda1, int K0,
    const unsigned short* __restrict__ W,
    const float* __restrict__ bias, void* __restrict__ outv, int M) {
    constexpr int NCHUNK = KTOT / 32;
    constexpr int NCT = NCOL / 16;     // 8 (NCOL=128) or 4 (NCOL=64)
    constexpr int CB = NCOL * 64;      // LDS bytes per chunk buffer (single bf16)
    constexpr int NI = NCOL / 16;      // 1KB stage instrs per chunk (per block)
    constexpr int NIW = NI / 4;        // per wave: 2 or 1
    constexpr int ASZ = (AFMT == 0) ? 2 : 1;  // u32x4 regs per A frag

    __shared__ unsigned char lds[2][CB];

    int wv = threadIdx.x >> 6;
    int lane = threadIdx.x & 63;
    int m16 = lane & 15;
    int quad = lane >> 4;
    int rowbase = blockIdx.x * 128 + wv * 32;

    int arow[2];
#pragma unroll
    for (int rt = 0; rt < 2; ++rt) {
        int r = rowbase + rt * 16 + m16;
        arow[rt] = (r < M) ? r : (M - 1);  // clamp reads; stores guarded below
    }

    // stage instr i: cols [i*16,+16); lane covers col i*16+(lane>>2), quarter lane&3 (8 bf16 = 16B)
    auto g_src = [&](int i, int kc) -> const unsigned short* {
        return W + (size_t)(i * 16 + (lane >> 2)) * KTOT + kc * 32 + (lane & 3) * 8;
    };
    auto dstoff = [&](int i) -> int { return i * 1024 + lane * 16; };
    auto aptr = [&](int kc, int rt) -> const void* {
        bool second = (kc * 32 >= K0);
        int lda = second ? lda1 : lda0;
        int kofs = kc * 32 - (second ? K0 : 0);
        if (AFMT == 0)
            return (const float*)(second ? A1v : A0v) + (size_t)arow[rt] * lda + kofs + quad * 8;
        else
            return (const unsigned short*)(second ? A1v : A0v) + (size_t)arow[rt] * lda + kofs + quad * 8;
    };

    f32x4 acc[2][NCT] = {};
    float bcol[NCT];
#pragma unroll
    for (int ct = 0; ct < NCT; ++ct) bcol[ct] = bias ? bias[ct * 16 + m16] : 0.f;

    // ---- prologue ----
    u32x4 stg[NIW];
#pragma unroll
    for (int ii = 0; ii < NIW; ++ii) stg[ii] = *(const u32x4*)(const void*)g_src(wv * NIW + ii, 0);
    u32x4 ra[2][ASZ];
#pragma unroll
    for (int rt = 0; rt < 2; ++rt) {
        const u32x4* p = (const u32x4*)aptr(0, rt);
        ra[rt][0] = p[0];
        if (AFMT == 0) ra[rt][1] = p[1];
    }
    // commit chunk0 into buf0 (waits on chunk0 loads)
#pragma unroll
    for (int ii = 0; ii < NIW; ++ii) *(u32x4*)(void*)(&lds[0][dstoff(wv * NIW + ii)]) = stg[ii];
    // issue chunk1 B loads (written at kc=0)
    if (NCHUNK > 1) {
#pragma unroll
        for (int ii = 0; ii < NIW; ++ii) stg[ii] = *(const u32x4*)(const void*)g_src(wv * NIW + ii, 1);
    }
    __syncthreads();  // buf0 visible

#pragma unroll
    for (int kc = 0; kc < NCHUNK; ++kc) {
        int p = kc & 1;

        // 1. write chunk kc+1 into buf[p^1]; issue chunk kc+2 B loads
        if (kc + 1 < NCHUNK) {
#pragma unroll
            for (int ii = 0; ii < NIW; ++ii) *(u32x4*)(void*)(&lds[p ^ 1][dstoff(wv * NIW + ii)]) = stg[ii];
            if (kc + 2 < NCHUNK) {
#pragma unroll
                for (int ii = 0; ii < NIW; ++ii) stg[ii] = *(const u32x4*)(const void*)g_src(wv * NIW + ii, kc + 2);
            }
        }

        // 2. issue next chunk's A loads -- fly during MFMA
        u32x4 na[2][ASZ];
        if (kc + 1 < NCHUNK) {
#pragma unroll
            for (int rt = 0; rt < 2; ++rt) {
                const u32x4* pn = (const u32x4*)aptr(kc + 1, rt);
                na[rt][0] = pn[0];
                if (AFMT == 0) na[rt][1] = pn[1];
            }
        }

        // 3. build A fragments (bf16 direct, or fp32 cvt for embed)
        short8 Ah[2];
#pragma unroll
        for (int rt = 0; rt < 2; ++rt) {
            if (AFMT == 0) {
                union { u32x4 u[2]; float f[8]; } cv;
                cv.u[0] = ra[rt][0];
                cv.u[1] = ra[rt][1];
#pragma unroll
                for (int j = 0; j < 8; ++j) Ah[rt][j] = (short)bf16_rne(cv.f[j]);
            } else {
                union { u32x4 u; short8 s; } cv;
                cv.u = ra[rt][0];
                Ah[rt] = cv.s;
            }
        }

        // 4. compute from buf[p]: per ct, 1 ds_read_b128 + 2 MFMAs
#pragma unroll
        for (int ct = 0; ct < NCT; ++ct) {
            const unsigned char* ph = &lds[p][(ct * 16 + m16) * 64 + quad * 16];
            short8 Bh = *(const short8*)(const void*)ph;
#pragma unroll
            for (int rt = 0; rt < 2; ++rt)
                acc[rt][ct] = __builtin_amdgcn_mfma_f32_16x16x32_bf16(Ah[rt], Bh, acc[rt][ct], 0, 0, 0);
        }

        if (kc + 1 < NCHUNK) {
#pragma unroll
            for (int rt = 0; rt < 2; ++rt) {
                ra[rt][0] = na[rt][0];
                if (AFMT == 0) ra[rt][1] = na[rt][1];
            }
        }

        __syncthreads();  // reads of buf[p] done; writes to buf[p^1] visible
    }

    // epilogue: C/D layout col = lane&15, row = quad*4 + reg
#pragma unroll
    for (int rt = 0; rt < 2; ++rt) {
#pragma unroll
        for (int r = 0; r < 4; ++r) {
            int row = rowbase + rt * 16 + quad * 4 + r;
            if (row < M) {
#pragma unroll
                for (int ct = 0; ct < NCT; ++ct) {
                    float v = acc[rt][ct][r] + bcol[ct];
                    if (RELU) v = fmaxf(v, 0.f);
                    size_t idx = (size_t)row * NCOL + ct * 16 + m16;
                    if (PACKOUT) ((unsigned short*)outv)[idx] = bf16_rne(v);
                    else ((float*)outv)[idx] = v;
                }
            }
        }
    }
}

// ---------------- aggregation (CSR gather-sum, bf16 rows, 4-wide pipelined MLP) ----------------
// x rows are bf16 [N][128] (u32 = 2 elems/lane, 64 lanes = full row, 256B/gather).
// fp32 accumulate; epilogue packs back to bf16.
__global__ void aggregate_kernel(const u32* __restrict__ x, const int* __restrict__ row_off,
                                 const int* __restrict__ csr, u32* __restrict__ agg, int N) {
    int gw = (blockIdx.x * 256 + threadIdx.x) >> 6;
    int lane = threadIdx.x & 63;
    if (gw >= N) return;
    int beg = row_off[gw], end = row_off[gw + 1];

    f2 a0 = (f2)0.f, a1 = (f2)0.f, a2 = (f2)0.f, a3 = (f2)0.f;

    auto unp = [](u32 u) -> f2 {
        f2 r;
        r[0] = __uint_as_float(u << 16);
        r[1] = __uint_as_float(u & 0xFFFF0000u);
        return r;
    };

    int nfull = (end - beg) >> 2;
    int j = beg;
    if (nfull > 0) {
        int s0 = csr[j], s1 = csr[j + 1], s2 = csr[j + 2], s3 = csr[j + 3];
        for (int b = 1; b < nfull; ++b) {
            u32 v0 = x[(size_t)s0 * 64 + lane];
            u32 v1 = x[(size_t)s1 * 64 + lane];
            u32 v2 = x[(size_t)s2 * 64 + lane];
            u32 v3 = x[(size_t)s3 * 64 + lane];
            int jn = j + 4;
            s0 = csr[jn]; s1 = csr[jn + 1]; s2 = csr[jn + 2]; s3 = csr[jn + 3];
            a0 += unp(v0); a1 += unp(v1); a2 += unp(v2); a3 += unp(v3);
            j = jn;
        }
        u32 v0 = x[(size_t)s0 * 64 + lane];
        u32 v1 = x[(size_t)s1 * 64 + lane];
        u32 v2 = x[(size_t)s2 * 64 + lane];
        u32 v3 = x[(size_t)s3 * 64 + lane];
        a0 += unp(v0); a1 += unp(v1); a2 += unp(v2); a3 += unp(v3);
        j += 4;
    }

    int rem = end - j;
    if (rem > 0) {
        int e1 = end - 1;
        int t0 = csr[j];
        int t1 = csr[min(j + 1, e1)];
        int t2 = csr[min(j + 2, e1)];
        u32 w0 = x[(size_t)t0 * 64 + lane];
        u32 w1 = x[(size_t)t1 * 64 + lane];
        u32 w2 = x[(size_t)t2 * 64 + lane];
        a0 += unp(w0);
        if (rem > 1) a1 += unp(w1);
        if (rem > 2) a2 += unp(w2);
    }

    f2 a = (a0 + a2) + (a1 + a3);
    agg[(size_t)gw * 64 + lane] = bf16x2_rne(a[0], a[1]);
}

// ---------------- edge head ----------------
// out[e][c] = pspd[src[e]][c] + pspd[dst[e]][32+c] + head_b[c]
__global__ void edge_out_kernel(const int* __restrict__ src, const int* __restrict__ dst,
                                const float* __restrict__ pspd, const float* __restrict__ head_b,
                                float* __restrict__ out, int E) {
    int idx = blockIdx.x * blockDim.x + threadIdx.x;
    int e = idx >> 3;
    int c4 = (idx & 7) * 4;
    if (e >= E) return;
    int s = src[e], d = dst[e];
    f4 a = *(const f4*)&pspd[(size_t)s * 64 + c4];
    f4 b = *(const f4*)&pspd[(size_t)d * 64 + 32 + c4];
    f4 hb = *(const f4*)&head_b[c4];
    f4 o = a + b + hb;
    *(f4*)&out[(size_t)e * CLASSES + c4] = o;
}

// ---------------- launcher ----------------

extern "C" void kernel_launch(void* const* d_in, const int* in_sizes, int n_in,
                              void* d_out, int out_size, void* d_ws, size_t ws_size,
                              hipStream_t stream) {
    const float* feat   = (const float*)d_in[0];
    const int*   eidx   = (const int*)d_in[1];
    const float* emb_w  = (const float*)d_in[2];
    const float* emb_b  = (const float*)d_in[3];
    const float* rel_w  = (const float*)d_in[4];
    const float* rel_b  = (const float*)d_in[5];
    const float* root_w = (const float*)d_in[6];
    const float* head_w = (const float*)d_in[7];
    const float* head_b = (const float*)d_in[8];
    float* out = (float*)d_out;

    int N = in_sizes[0] / FEAT;
    int E = in_sizes[1] / 2;
    const int* src = eidx;
    const int* dst = eidx + E;

    // workspace layout: bf16 activation buffers (as u32 regions), pspd fp32 aliases agg,
    // then ints, then single-bf16 weight tables
    u32* xA  = (u32*)d_ws;                  // N*64 u32 = N*128 bf16
    u32* xB  = xA + (size_t)N * 64;         // N*64 u32
    u32* agg = xB + (size_t)N * 64;         // N*64 u32 (pspd aliases: N*64 fp32 = same bytes)
    int* counts   = (int*)(agg + (size_t)N * 64);   // N
    int* row_off  = counts + N;                     // N+1
    int* cursor   = row_off + (N + 1);              // N
    int* csr_src  = cursor + N;                     // E
    int* partials = csr_src + E;                    // 256
    int* poff     = partials + 256;                 // 256
    int* iend     = poff + 256;
    // pad int region to 16B boundary
    size_t ioff = (size_t)(iend - (int*)d_ws);
    ioff = (ioff + 3) & ~(size_t)3;
    unsigned short* we = (unsigned short*)((int*)d_ws + ioff);  // 128*256
    unsigned short* wl = we + 128 * 256;                        // 3*128*256
    unsigned short* wp = wl + 3 * 128 * 256;                    // 64*128

    int NB = (N + 255) / 256;

    hipMemsetAsync(counts, 0, (size_t)N * sizeof(int), stream);
    count_kernel<<<(E + 255) / 256, 256, 0, stream>>>(dst, counts, E);
    partial_kernel<<<NB, 256, 0, stream>>>(counts, partials, N);
    scan_partials_kernel<<<1, 256, 0, stream>>>(partials, poff, NB);
    scan_final_kernel<<<NB, 256, 0, stream>>>(counts, poff, row_off, cursor, N);
    fill_kernel<<<(E + 255) / 256, 256, 0, stream>>>(src, dst, cursor, csr_src, E);

    prep_emb_kernel<<<(128 * 256 + 255) / 256, 256, 0, stream>>>(emb_w, we);
    prep_layer_kernel<<<(3 * 128 * 256 + 255) / 256, 256, 0, stream>>>(rel_w, root_w, wl);
    prep_head_kernel<<<(64 * 128 + 255) / 256, 256, 0, stream>>>(head_w, wp);

    int grid = (N + 127) / 128;
    // embed: xA = bf16(relu(feat @ emb_w + emb_b)); A fp32
    gemm_mfma<HID, FEAT, true, 0, true><<<grid, 256, 0, stream>>>(
        feat, FEAT, nullptr, 0, FEAT, we, emb_b, xA, N);

    const u32* xin = xA;
    u32* xout = xB;
    for (int l = 0; l < LAYERS; ++l) {
        aggregate_kernel<<<(N * 64 + 255) / 256, 256, 0, stream>>>(xin, row_off, csr_src, agg, N);
        gemm_mfma<HID, 2 * HID, true, 1, true><<<grid, 256, 0, stream>>>(
            agg, HID, xin, HID, HID,
            wl + (size_t)l * 128 * 256, rel_b + (size_t)l * HID, xout, N);
        u32* tmp = (u32*)xin; xin = xout; xout = tmp;
    }

    // pspd = x @ Wpp (no bias/relu), fp32 out; aliases agg
    float* pspd = (float*)agg;
    gemm_mfma<64, HID, false, 1, false><<<grid, 256, 0, stream>>>(
        xin, HID, nullptr, 0, HID, wp, nullptr, pspd, N);

    edge_out_kernel<<<((size_t)E * 8 + 255) / 256, 256, 0, stream>>>(src, dst, pspd, head_b, out, E);
}